// Round 2
// baseline (33.779 us; speedup 1.0000x reference)
//
#include <hip/hip_runtime.h>
#include <hip/hip_cooperative_groups.h>

namespace cg = cooperative_groups;

#define BB 128
#define DD 1024
#define LAMBDA_COEFF 0.005f

// Fused single-dispatch kernel (cooperative launch, grid.sync between phases).
// Grid = 128 blocks x 256 threads.
//
// Phase 1: column stats. Block b handles 16 of the 2048 combined columns
//          (cols [0,1024) -> z1, [1024,2048) -> z2). stats layout in d_ws:
//          [0,2D) means, [2D,4D) rstd (ddof=1).
// Phase 2: block i = sample i, closed-form loss from per-row power sums.
__global__ __launch_bounds__(256) void bt_fused(const float* __restrict__ z1,
                                                const float* __restrict__ z2,
                                                float* __restrict__ stats,
                                                float* __restrict__ out) {
    cg::grid_group grid = cg::this_grid();
    const int tid = threadIdx.x;

    // ------------------------------ Phase 1 ------------------------------
    {
        const int c = tid & 15;          // column within this block's 16
        const int g = tid >> 4;          // row group 0..15 (8 rows each)
        const int colIdx = blockIdx.x * 16 + c;   // 0..2047
        const float* __restrict__ z = (colIdx < DD) ? z1 : z2;
        const int col = colIdx & (DD - 1);

        float s = 0.f, ss = 0.f;
#pragma unroll
        for (int r = 0; r < 8; ++r) {
            float v = z[(g * 8 + r) * DD + col];
            s += v;
            ss += v * v;
        }

        __shared__ float sh_s[16][16];
        __shared__ float sh_ss[16][16];
        sh_s[g][c] = s;
        sh_ss[g][c] = ss;
        __syncthreads();

        if (tid < 16) {
            float S = 0.f, SS = 0.f;
#pragma unroll
            for (int gg = 0; gg < 16; ++gg) {
                S += sh_s[gg][tid];
                SS += sh_ss[gg][tid];
            }
            const int ci = blockIdx.x * 16 + tid;
            float mu  = S * (1.0f / BB);
            float var = (SS - (float)BB * mu * mu) * (1.0f / (BB - 1));
            stats[ci]          = mu;
            stats[2 * DD + ci] = rsqrtf(var);
        }
    }

    grid.sync();  // device-scope barrier: stats now visible to all blocks

    // ------------------------------ Phase 2 ------------------------------
    const int i = blockIdx.x;  // sample

    const float4* __restrict__ z1r = (const float4*)(z1 + i * DD);
    const float4* __restrict__ z2r = (const float4*)(z2 + i * DD);
    const float4* __restrict__ mu1 = (const float4*)(stats);
    const float4* __restrict__ mu2 = (const float4*)(stats + DD);
    const float4* __restrict__ rs1 = (const float4*)(stats + 2 * DD);
    const float4* __restrict__ rs2 = (const float4*)(stats + 3 * DD);

    float4 x1 = z1r[tid], x2 = z2r[tid];
    float4 m1 = mu1[tid], m2 = mu2[tid];
    float4 r1 = rs1[tid], r2 = rs2[tid];

    float a[4] = {(x1.x - m1.x) * r1.x, (x1.y - m1.y) * r1.y,
                  (x1.z - m1.z) * r1.z, (x1.w - m1.w) * r1.w};
    float b[4] = {(x2.x - m2.x) * r2.x, (x2.y - m2.y) * r2.y,
                  (x2.z - m2.z) * r2.z, (x2.w - m2.w) * r2.w};

    __shared__ float sh_ab[2];  // a_i, b_i (the (i,i) normalized entries)

    // per-thread partial power sums
    // vals: 0=R1=Σ(d-1)^2 1=A2=Σa^2 2=S1=Σb 3=S2=Σb^2 4=S3=Σb^3 5=S4=Σb^4 6=C2=Σd^2
    float vals[7] = {0.f, 0.f, 0.f, 0.f, 0.f, 0.f, 0.f};
#pragma unroll
    for (int k = 0; k < 4; ++k) {
        const int d = tid * 4 + k;
        float ak = a[k], bk = b[k];
        float dk = ak * bk;
        float ek = dk - 1.f;
        float b2 = bk * bk;
        vals[0] += ek * ek;
        vals[1] += ak * ak;
        vals[2] += bk;
        vals[3] += b2;
        vals[4] += b2 * bk;
        vals[5] += b2 * b2;
        vals[6] += dk * dk;
        if (d == i) { sh_ab[0] = ak; sh_ab[1] = bk; }
    }

    // wave64 butterfly reduce, then cross-wave via LDS
#pragma unroll
    for (int off = 32; off >= 1; off >>= 1) {
#pragma unroll
        for (int k = 0; k < 7; ++k) vals[k] += __shfl_down(vals[k], off, 64);
    }

    __shared__ float sh_red[4][7];
    const int wave = tid >> 6;
    const int lane = tid & 63;
    if (lane == 0) {
#pragma unroll
        for (int k = 0; k < 7; ++k) sh_red[wave][k] = vals[k];
    }
    __syncthreads();

    if (tid == 0) {
        float R1 = sh_red[0][0] + sh_red[1][0] + sh_red[2][0] + sh_red[3][0];
        float A2 = sh_red[0][1] + sh_red[1][1] + sh_red[2][1] + sh_red[3][1];
        float S1 = sh_red[0][2] + sh_red[1][2] + sh_red[2][2] + sh_red[3][2];
        float S2 = sh_red[0][3] + sh_red[1][3] + sh_red[2][3] + sh_red[3][3];
        float S3 = sh_red[0][4] + sh_red[1][4] + sh_red[2][4] + sh_red[3][4];
        float S4 = sh_red[0][5] + sh_red[1][5] + sh_red[2][5] + sh_red[3][5];
        float C2 = sh_red[0][6] + sh_red[1][6] + sh_red[2][6] + sh_red[3][6];

        float ai = sh_ab[0];
        float bi = sh_ab[1];
        float di = ai * bi;
        float e  = di - 1.f;
        float e2 = e * e;

        // on_diag: Σ_j (d_j-1)^2 with j==i term replaced by ((d_i-1)^2 - 1)^2
        float on = R1 - e2 + (e2 - 1.f) * (e2 - 1.f);

        // off_diag:
        //   row i (p==i):    Σ_q (a_i b_q - 1)^4 - (d_i-1)^4
        //   rows p!=i, q!=p: (A2 - a_i^2)*S2 - (C2 - d_i^2)
        float u  = ai;
        float u2 = u * u;
        float T4all = u2 * u2 * S4 - 4.f * u2 * u * S3 + 6.f * u2 * S2
                      - 4.f * u * S1 + (float)DD;
        float off = (T4all - e2 * e2) + (A2 - u2) * S2 - C2 + di * di;

        out[i] = on + LAMBDA_COEFF * off;
    }
}

extern "C" void kernel_launch(void* const* d_in, const int* in_sizes, int n_in,
                              void* d_out, int out_size, void* d_ws, size_t ws_size,
                              hipStream_t stream) {
    const float* z1 = (const float*)d_in[0];
    const float* z2 = (const float*)d_in[1];
    float* out   = (float*)d_out;
    float* stats = (float*)d_ws;  // 4*D floats = 16 KB

    void* args[] = {(void*)&z1, (void*)&z2, (void*)&stats, (void*)&out};
    hipLaunchCooperativeKernel((void*)bt_fused, dim3(BB), dim3(256), args, 0, stream);
}

// Round 3
// 12.091 us; speedup vs baseline: 2.7937x; 2.7937x over previous
//
#include <hip/hip_runtime.h>

#define BB 128
#define DD 1024
#define LAMBDA_COEFF 0.005f
#define NWORK 32          // worker blocks; each owns DD/NWORK = 32 column-pairs
#define MAGIC 0x7F3A91C5u

// Single-dispatch BarlowTwins loss.
//
// ws layout (floats):
//   [0, NWORK*BB*8)        part: per (worker-block, sample) 7 power sums (pad 8)
//                          stored as 2x float4 at index (b*BB + s)*2
//   [NWORK*BB*8, +BB)      diagA: a_ii = z1n[i][i]
//   [+BB, +BB)             diagB: b_ii = z2n[i][i]
//   then NWORK uints       flags (release/acquire, agent scope)
//
// Worker block b (b < NWORK), 256 threads: t -> c4 = t&7 (float4 col group),
// g = t>>3 (4-row group). Owns cols [32b, 32b+32).
//   1. load 4 rows x 4 cols of z1,z2 (8x float4, coalesced 128B clusters)
//   2. column stats: butterfly over g within wave (xor 8,16,32) + LDS across 4 waves
//   3. normalize in-register; write diag elems (col j == row r)
//   4. per-row 7 partial sums over its 4 cols; butterfly over c4 (xor 1,2,4);
//      c4==0 lanes store part[b][r] (plain stores, fixed order -> deterministic)
//   5. __threadfence + release-store flag[b] = MAGIC
//
// Finalizer block (b == NWORK): acquire-spin on 32 flags, then thread s<128
// sums part[*][s] in fixed b-order and applies the closed form:
//   on  = R1 - e^2 + (e^2-1)^2,            e = a_i b_i - 1
//   off = (u^4 S4 - 4u^3 S3 + 6u^2 S2 - 4u S1 + D - e^4) + (A2-u^2) S2 - C2 + d_i^2
__global__ __launch_bounds__(256) void bt_one(const float* __restrict__ z1,
                                              const float* __restrict__ z2,
                                              float* __restrict__ ws,
                                              float* __restrict__ out) {
    float4* part   = (float4*)ws;                         // NWORK*BB*2 float4
    float*  diagA  = ws + NWORK * BB * 8;                 // BB floats
    float*  diagB  = diagA + BB;                          // BB floats
    unsigned* flags = (unsigned*)(diagB + BB);            // NWORK uints

    const int tid = threadIdx.x;
    const int blk = blockIdx.x;

    if (blk < NWORK) {
        // ---------------- worker ----------------
        const int c4 = tid & 7;          // float4 column group within block
        const int g  = tid >> 3;         // 4-row group, 0..31
        const int col0 = blk * 32 + c4 * 4;

        float4 xa[4], xb[4];
#pragma unroll
        for (int rr = 0; rr < 4; ++rr) {
            const int r = g * 4 + rr;
            xa[rr] = *(const float4*)&z1[r * DD + col0];
            xb[rr] = *(const float4*)&z2[r * DD + col0];
        }

        // per-column partial sums over this thread's 4 rows
        float s1[4] = {0, 0, 0, 0}, q1[4] = {0, 0, 0, 0};
        float s2[4] = {0, 0, 0, 0}, q2[4] = {0, 0, 0, 0};
#pragma unroll
        for (int rr = 0; rr < 4; ++rr) {
            const float* pa = (const float*)&xa[rr];
            const float* pb = (const float*)&xb[rr];
#pragma unroll
            for (int k = 0; k < 4; ++k) {
                s1[k] += pa[k]; q1[k] += pa[k] * pa[k];
                s2[k] += pb[k]; q2[k] += pb[k] * pb[k];
            }
        }
        // reduce over g within wave: lanes differing in bits 3,4,5 share c4
#pragma unroll
        for (int m = 8; m <= 32; m <<= 1) {
#pragma unroll
            for (int k = 0; k < 4; ++k) {
                s1[k] += __shfl_xor(s1[k], m, 64);
                q1[k] += __shfl_xor(q1[k], m, 64);
                s2[k] += __shfl_xor(s2[k], m, 64);
                q2[k] += __shfl_xor(q2[k], m, 64);
            }
        }
        // combine 4 waves via LDS
        __shared__ float shst[4][8][16];  // [wave][c4][s1(4) q1(4) s2(4) q2(4)]
        const int wave = tid >> 6;
        if ((tid & 56) == 0) {  // one lane per (wave, c4)
#pragma unroll
            for (int k = 0; k < 4; ++k) {
                shst[wave][c4][k]      = s1[k];
                shst[wave][c4][4 + k]  = q1[k];
                shst[wave][c4][8 + k]  = s2[k];
                shst[wave][c4][12 + k] = q2[k];
            }
        }
        __syncthreads();

        float mu1[4], r1[4], mu2[4], r2[4];
#pragma unroll
        for (int k = 0; k < 4; ++k) {
            float S1 = 0, Q1 = 0, S2 = 0, Q2 = 0;
#pragma unroll
            for (int w = 0; w < 4; ++w) {
                S1 += shst[w][c4][k];
                Q1 += shst[w][c4][4 + k];
                S2 += shst[w][c4][8 + k];
                Q2 += shst[w][c4][12 + k];
            }
            mu1[k] = S1 * (1.0f / BB);
            r1[k]  = rsqrtf((Q1 - (float)BB * mu1[k] * mu1[k]) * (1.0f / (BB - 1)));
            mu2[k] = S2 * (1.0f / BB);
            r2[k]  = rsqrtf((Q2 - (float)BB * mu2[k] * mu2[k]) * (1.0f / (BB - 1)));
        }

        // normalize + per-row partial sums; capture diagonal
        // vals: 0=R1=Σ(d-1)^2 1=A2=Σa^2 2=S1=Σb 3=S2=Σb^2 4=S3=Σb^3 5=S4=Σb^4 6=C2=Σd^2
        float p[4][7];
#pragma unroll
        for (int rr = 0; rr < 4; ++rr) {
            const int r = g * 4 + rr;
            const float* pa = (const float*)&xa[rr];
            const float* pb = (const float*)&xb[rr];
#pragma unroll
            for (int k = 0; k < 7; ++k) p[rr][k] = 0.f;
#pragma unroll
            for (int k = 0; k < 4; ++k) {
                float a = (pa[k] - mu1[k]) * r1[k];
                float b = (pb[k] - mu2[k]) * r2[k];
                float d = a * b;
                float e = d - 1.f;
                float b2 = b * b;
                p[rr][0] += e * e;
                p[rr][1] += a * a;
                p[rr][2] += b;
                p[rr][3] += b2;
                p[rr][4] += b2 * b;
                p[rr][5] += b2 * b2;
                p[rr][6] += d * d;
                if (col0 + k == r) { diagA[r] = a; diagB[r] = b; }
            }
        }
        // reduce over c4 (lane bits 0..2)
#pragma unroll
        for (int m = 1; m <= 4; m <<= 1) {
#pragma unroll
            for (int rr = 0; rr < 4; ++rr)
#pragma unroll
                for (int k = 0; k < 7; ++k)
                    p[rr][k] += __shfl_xor(p[rr][k], m, 64);
        }
        if (c4 == 0) {
#pragma unroll
            for (int rr = 0; rr < 4; ++rr) {
                const int r = g * 4 + rr;
                float4 lo = make_float4(p[rr][0], p[rr][1], p[rr][2], p[rr][3]);
                float4 hi = make_float4(p[rr][4], p[rr][5], p[rr][6], 0.f);
                part[(blk * BB + r) * 2]     = lo;
                part[(blk * BB + r) * 2 + 1] = hi;
            }
        }

        __syncthreads();
        __threadfence();  // make part/diag visible at agent scope
        if (tid == 0)
            __hip_atomic_store(&flags[blk], MAGIC, __ATOMIC_RELEASE,
                               __HIP_MEMORY_SCOPE_AGENT);
    } else {
        // ---------------- finalizer ----------------
        if (tid < NWORK) {
            while (__hip_atomic_load(&flags[tid], __ATOMIC_ACQUIRE,
                                     __HIP_MEMORY_SCOPE_AGENT) != MAGIC) {
                __builtin_amdgcn_s_sleep(8);
            }
        }
        __syncthreads();

        if (tid < BB) {
            const int s = tid;
            float R1 = 0, A2 = 0, S1 = 0, S2 = 0, S3 = 0, S4 = 0, C2 = 0;
#pragma unroll 4
            for (int b = 0; b < NWORK; ++b) {
                float4 lo = part[(b * BB + s) * 2];
                float4 hi = part[(b * BB + s) * 2 + 1];
                R1 += lo.x; A2 += lo.y; S1 += lo.z; S2 += lo.w;
                S3 += hi.x; S4 += hi.y; C2 += hi.z;
            }
            const float ai = diagA[s];
            const float bi = diagB[s];
            const float di = ai * bi;
            const float e  = di - 1.f;
            const float e2 = e * e;

            float on = R1 - e2 + (e2 - 1.f) * (e2 - 1.f);

            const float u  = ai;
            const float u2 = u * u;
            float T4all = u2 * u2 * S4 - 4.f * u2 * u * S3 + 6.f * u2 * S2
                          - 4.f * u * S1 + (float)DD;
            float off = (T4all - e2 * e2) + (A2 - u2) * S2 - C2 + di * di;

            out[s] = on + LAMBDA_COEFF * off;
        }
    }
}

extern "C" void kernel_launch(void* const* d_in, const int* in_sizes, int n_in,
                              void* d_out, int out_size, void* d_ws, size_t ws_size,
                              hipStream_t stream) {
    const float* z1 = (const float*)d_in[0];
    const float* z2 = (const float*)d_in[1];
    float* out = (float*)d_out;
    float* ws  = (float*)d_ws;

    bt_one<<<NWORK + 1, 256, 0, stream>>>(z1, z2, ws, out);
}